// Round 2
// baseline (286.321 us; speedup 1.0000x reference)
//
#include <hip/hip_runtime.h>
#include <hip/hip_bf16.h>

#define NN 100000
#define EE 1600000
#define ETOT 1700000   // EE + NN self loops
#define FIN1 128
#define HD 64
#define NC 10
#define NB 128
#define NEG 0.2f
#define LOG2E 1.44269504f

#define NBKT 196       // ceil(NN/512)
#define BCAP 10240     // per-bucket capacity (mean 8673, sd ~93)
#define BLKE 4096      // edges per bucketA block (round-19 2048 regressed: fragmentation)
#define ABLOCKS ((ETOT + BLKE - 1) / BLKE)   // 416
#define GBLOCKS ((NN + 63) / 64)             // 1563

// Input dtypes: floats fp32, integers int32 (harness spec; round-16 verified).

// workspace layout (bytes)
static constexpr size_t OFF_HA   = 0;                                // 6.4 MB
static constexpr size_t OFF_HB   = (size_t)NN * HD;                  // 6.4 MB
static constexpr size_t OFF_ESA  = (size_t)NN * HD * 2;
static constexpr size_t OFF_EDA  = OFF_ESA + (size_t)NN * 4;
static constexpr size_t OFF_ESB  = OFF_EDA + (size_t)NN * 4;
static constexpr size_t OFF_EDB  = OFF_ESB + (size_t)NN * 4;
static constexpr size_t OFF_ROW  = OFF_EDB + (size_t)NN * 4;         // rowptr[NN+1]
static constexpr size_t OFF_CSR  = OFF_ROW + (size_t)(NN + 4) * 4;   // 6.8 MB
static constexpr size_t OFF_GC   = OFF_CSR + (size_t)ETOT * 4;       // 1024 B
static constexpr size_t OFF_POOL = OFF_GC + 1024;                    // 32 KB (gcur+pooled: one memset)
static constexpr size_t OFF_BKT  = OFF_POOL + (size_t)NB * HD * 4;   // 8.03 MB
// total ~29.8 MB

typedef __attribute__((ext_vector_type(8))) short short8;   // 8 bf16 = 4 VGPR
typedef __attribute__((ext_vector_type(4))) float floatx4;
typedef __attribute__((ext_vector_type(2))) float floatx2;

__device__ __forceinline__ unsigned short f2bf(float f) {
  unsigned u = __float_as_uint(f);
  if ((u & 0x7F800000u) == 0x7F800000u) return (unsigned short)(u >> 16);
  return (unsigned short)((u + 0x7FFFu + ((u >> 16) & 1u)) >> 16);
}
__device__ __forceinline__ unsigned pk2(float a, float b) {
  return (unsigned)f2bf(a) | ((unsigned)f2bf(b) << 16);
}

// ---- fp8 e4m3 pack/unpack (HW builtins on gfx950; manual fallback) ----
#if __has_builtin(__builtin_amdgcn_cvt_pk_fp8_f32) && __has_builtin(__builtin_amdgcn_cvt_pk_f32_fp8)
#define HW_FP8 1
#endif
__device__ __forceinline__ unsigned enc1_fp8(float f) {
  _Float16 hf = (_Float16)f;
  unsigned short b = __builtin_bit_cast(unsigned short, hf);
  unsigned s = ((unsigned)b >> 8) & 0x80u;
  int mag = b & 0x7fff;
  if (mag < 0x2380) return s;
  int r = mag + 0x3F + ((mag >> 7) & 1);
  int m = (r >> 7) - 64;
  if (m > 0x7E) m = 0x7E;
  return s | (unsigned)m;
}
__device__ __forceinline__ unsigned pack4_fp8(float a, float b, float c, float d) {
#ifdef HW_FP8
  int w = __builtin_amdgcn_cvt_pk_fp8_f32(a, b, 0, false);
  w = __builtin_amdgcn_cvt_pk_fp8_f32(c, d, w, true);
  return (unsigned)w;
#else
  return enc1_fp8(a) | (enc1_fp8(b) << 8) | (enc1_fp8(c) << 16) | (enc1_fp8(d) << 24);
#endif
}
__device__ __forceinline__ float dec1_fp8(unsigned byte) {
  unsigned short hb = (unsigned short)(((byte & 0x80u) << 8) | ((byte & 0x7fu) << 7));
  _Float16 hf = __builtin_bit_cast(_Float16, hb);
  return (float)hf * 256.0f;
}
template <bool HI>
__device__ __forceinline__ floatx2 unpk2_fp8(unsigned w) {
#ifdef HW_FP8
  return __builtin_amdgcn_cvt_pk_f32_fp8((int)w, HI);
#else
  unsigned s = HI ? (w >> 16) : w;
  floatx2 r; r.x = dec1_fp8(s & 0xffu); r.y = dec1_fp8((s >> 8) & 0xffu);
  return r;
#endif
}

// 16-feature fp8 accumulate: acc[j] += w * feature[j]
__device__ __forceinline__ void acc16(float* acc, float w, uint4 u) {
  floatx2 f0 = unpk2_fp8<false>(u.x), f1 = unpk2_fp8<true>(u.x);
  floatx2 f2 = unpk2_fp8<false>(u.y), f3 = unpk2_fp8<true>(u.y);
  floatx2 f4 = unpk2_fp8<false>(u.z), f5 = unpk2_fp8<true>(u.z);
  floatx2 f6 = unpk2_fp8<false>(u.w), f7 = unpk2_fp8<true>(u.w);
  acc[0]  = fmaf(w, f0.x, acc[0]);  acc[1]  = fmaf(w, f0.y, acc[1]);
  acc[2]  = fmaf(w, f1.x, acc[2]);  acc[3]  = fmaf(w, f1.y, acc[3]);
  acc[4]  = fmaf(w, f2.x, acc[4]);  acc[5]  = fmaf(w, f2.y, acc[5]);
  acc[6]  = fmaf(w, f3.x, acc[6]);  acc[7]  = fmaf(w, f3.y, acc[7]);
  acc[8]  = fmaf(w, f4.x, acc[8]);  acc[9]  = fmaf(w, f4.y, acc[9]);
  acc[10] = fmaf(w, f5.x, acc[10]); acc[11] = fmaf(w, f5.y, acc[11]);
  acc[12] = fmaf(w, f6.x, acc[12]); acc[13] = fmaf(w, f6.y, acc[13]);
  acc[14] = fmaf(w, f7.x, acc[14]); acc[15] = fmaf(w, f7.y, acc[15]);
}

// ROUND-22: aggregation core, 4 lanes per node (fl = t&3).
// Round-21 post-mortem: loop is bound by divergent vmem lane-request
// throughput (~24 lane-reqs/edge: 8x8B h + 8x replicated csr + 8x replicated
// es); unroll 4->8 scaled time with padded slots, VALUBusy stuck at 42%.
// New structure: lane fl owns edge i+fl (csr+es gather+exp2 ONCE per edge,
// 1 lane-req each), sources/weights distributed via __shfl width-4; h read
// as uint4 (4x16B lane-reqs per edge). ~24 -> ~6 lane-reqs/edge, 8x less
// transcendental work. Returns inv-denominator; acc[16] = weighted sums for
// features [16*fl, 16*fl+16).
__device__ __forceinline__ float aggregate_node(
    int n, int fl, const int* __restrict__ rowptr, const int* __restrict__ csr,
    const float* __restrict__ esIn, const float* __restrict__ edIn,
    const uint4* __restrict__ h16, float* acc) {
#pragma unroll
  for (int j = 0; j < 16; j++) acc[j] = 0.f;
  const float edn = edIn[n];
  const int row = rowptr[n];
  const int end = rowptr[n + 1];
  const int endm1 = end - 1;
  float den = 0.f;
  int idx0 = row + fl;
  int s_cur = csr[(idx0 < end) ? idx0 : endm1];
  float ev_cur = esIn[s_cur];
  for (int i = row; i < end; i += 4) {
    // one-deep software prefetch of next csr+es (off the critical path)
    int inext = i + 4;
    int s_nxt = s_cur;
    if (inext < end) {
      int idn = inext + fl;
      s_nxt = csr[(idn < end) ? idn : endm1];
    }
    float ev_nxt = esIn[s_nxt];
    // weight for MY edge only (1 leaky+exp2 per edge, not per lane)
    float e = ev_cur + edn;
    e = fmaxf(e, NEG * e);
    float w = exp2f(e);
    w = (i + fl < end) ? w : 0.f;
    den += w;
    // distribute src + weight to the 4 cluster lanes
    int s0 = __shfl(s_cur, 0, 4), s1 = __shfl(s_cur, 1, 4);
    int s2 = __shfl(s_cur, 2, 4), s3 = __shfl(s_cur, 3, 4);
    float w0 = __shfl(w, 0, 4), w1 = __shfl(w, 1, 4);
    float w2 = __shfl(w, 2, 4), w3 = __shfl(w, 3, 4);
    uint4 u0 = h16[s0 * 4 + fl];
    uint4 u1 = h16[s1 * 4 + fl];
    uint4 u2 = h16[s2 * 4 + fl];
    uint4 u3 = h16[s3 * 4 + fl];
    acc16(acc, w0, u0);
    acc16(acc, w1, u1);
    acc16(acc, w2, u2);
    acc16(acc, w3, u3);
    s_cur = s_nxt;
    ev_cur = ev_nxt;
  }
  den += __shfl_xor(den, 1, 4);
  den += __shfl_xor(den, 2, 4);
  return 1.0f / den;
}

// ---------------- bucketA body: LDS-staged, bucket-sorted COALESCED writes ----------------
__device__ __forceinline__ void bucketA_body(
    int bid, const int* __restrict__ EI, unsigned* __restrict__ bucketed,
    int* __restrict__ gcur, char* smem) {
  unsigned* stage = (unsigned*)smem;                        // BLKE words   16 KB
  unsigned short* sb = (unsigned short*)(smem + BLKE * 4);  // BLKE shorts   8 KB
  int* cnt  = (int*)(smem + BLKE * 4 + BLKE * 2);           // NBKT
  int* lofs = cnt + NBKT;                                   // NBKT
  int* base = lofs + NBKT;                                  // NBKT
  int* sc   = base + NBKT;                                  // 256
  const int t = threadIdx.x;
  const long long start = (long long)bid * BLKE;
  long long rem = (long long)ETOT - start;
  const int V = (rem < BLKE) ? (int)rem : BLKE;
  unsigned pk[BLKE / 256];
  short bk[BLKE / 256];
  for (int i = t; i < NBKT; i += 256) cnt[i] = 0;
  __syncthreads();
#pragma unroll
  for (int j = 0; j < BLKE / 256; j++) {
    long long k = start + t + 256 * j;
    bk[j] = -1;
    if (k < ETOT) {
      int s, d;
      if (k < EE) { s = EI[k]; d = EI[(long long)EE + k]; }
      else        { s = d = (int)(k - EE); }
      int b = d >> 9;
      pk[j] = ((unsigned)s << 9) | (unsigned)(d & 511);
      bk[j] = (short)b;
      atomicAdd(&cnt[b], 1);
    }
  }
  __syncthreads();
  // exclusive scan of cnt -> lofs; reserve global space; reset cnt as cursor
  int own = (t < NBKT) ? cnt[t] : 0;
  sc[t] = own;
  __syncthreads();
  for (int off = 1; off < 256; off <<= 1) {
    int add = (t >= off) ? sc[t - off] : 0;
    __syncthreads();
    sc[t] += add;
    __syncthreads();
  }
  if (t < NBKT) {
    lofs[t] = sc[t] - own;
    base[t] = (own > 0) ? atomicAdd(&gcur[t], own) : 0;
    cnt[t] = 0;
  }
  __syncthreads();
  // scatter into LDS staging (sorted by bucket)
#pragma unroll
  for (int j = 0; j < BLKE / 256; j++) {
    if (bk[j] >= 0) {
      int b = bk[j];
      int p = lofs[b] + atomicAdd(&cnt[b], 1);
      stage[p] = pk[j];
      sb[p] = (unsigned short)b;
    }
  }
  __syncthreads();
  // coalesced copy-out: entry i -> bucketed[b*BCAP + base[b] + (i - lofs[b])]
  for (int i = t; i < V; i += 256) {
    int b = sb[i];
    int pos = base[b] + (i - lofs[b]);
    if (pos < BCAP) bucketed[(long long)b * BCAP + pos] = stage[i];
  }
}

// ---------------- gemm1 body: h1 = x@W1^T from fp32 input (MFMA) ----------------
__device__ __forceinline__ void gemm1_body(
    int bid, const float* __restrict__ X, const float* __restrict__ W,
    const float* __restrict__ As, const float* __restrict__ Ad,
    unsigned* __restrict__ hout, float* __restrict__ es, float* __restrict__ ed,
    char* smem) {
  constexpr int K = FIN1, RW = K / 2;
  unsigned* Xw = (unsigned*)smem;             // 16 KB
  unsigned* Ww = (unsigned*)(smem + 16384);   // 16 KB
  const int t = threadIdx.x;
  const int nodeBase = bid * 64;

  for (int i4 = t * 4; i4 < 64 * K; i4 += 1024) {
    int node = i4 >> 7, k = i4 & (K - 1);
    float4 v = make_float4(0.f, 0.f, 0.f, 0.f);
    if (nodeBase + node < NN)
      v = *(const float4*)(X + ((long long)(nodeBase + node) << 7) + k);
    uint2 p = make_uint2(pk2(v.x, v.y), pk2(v.z, v.w));
    int kw = k >> 1;
    *(uint2*)&Xw[node * RW + (kw ^ ((node & 7) << 2))] = p;
  }
  for (int i4 = t * 4; i4 < 64 * K; i4 += 1024) {
    int f = i4 >> 7, k = i4 & (K - 1);
    float4 v = *(const float4*)(W + ((long long)f << 7) + k);
    uint2 p = make_uint2(pk2(v.x, v.y), pk2(v.z, v.w));
    int kw = k >> 1;
    *(uint2*)&Ww[f * RW + (kw ^ ((f & 7) << 2))] = p;
  }
  __syncthreads();

  const int w = t >> 6, l = t & 63, m = l & 15, q = l >> 4;
  const int nodeLoc = 16 * w + m;
  const int sxa = (nodeLoc & 7) << 2;
  floatx4 acc[4];
#pragma unroll
  for (int nt = 0; nt < 4; nt++) acc[nt] = (floatx4){0.f, 0.f, 0.f, 0.f};
#pragma unroll
  for (int kc = 0; kc < K; kc += 32) {
    const int kcw = (kc >> 1) + 4 * q;
    short8 af = *(const short8*)&Xw[nodeLoc * RW + (kcw ^ sxa)];
#pragma unroll
    for (int nt = 0; nt < 4; nt++) {
      int f = 16 * nt + m;
      short8 bf = *(const short8*)&Ww[f * RW + (kcw ^ ((f & 7) << 2))];
      acc[nt] = __builtin_amdgcn_mfma_f32_16x16x32_bf16(af, bf, acc[nt], 0, 0, 0);
    }
  }
  float asv[4], adv[4];
#pragma unroll
  for (int nt = 0; nt < 4; nt++) { asv[nt] = As[16 * nt + m]; adv[nt] = Ad[16 * nt + m]; }
#pragma unroll
  for (int r = 0; r < 4; r++) {
    float ss = 0.f, sd2 = 0.f;
#pragma unroll
    for (int nt = 0; nt < 4; nt++) {
      ss = fmaf(acc[nt][r], asv[nt], ss);
      sd2 = fmaf(acc[nt][r], adv[nt], sd2);
    }
#pragma unroll
    for (int off = 1; off < 16; off <<= 1) {
      ss += __shfl_xor(ss, off);
      sd2 += __shfl_xor(sd2, off);
    }
    if (m == 0) {
      int gn = nodeBase + 16 * w + 4 * q + r;
      if (gn < NN) { es[gn] = ss * LOG2E; ed[gn] = sd2 * LOG2E; }
    }
  }
  {
    int gn = nodeBase + 16 * w + 4 * q;
#pragma unroll
    for (int nt = 0; nt < 4; nt++) {
#pragma unroll
      for (int r = 0; r < 4; r++) {
        float v = acc[nt][r];
        float p1 = __shfl_xor(v, 1);
        float p2 = __shfl_xor(v, 2);
        float p3 = __shfl_xor(v, 3);
        if ((m & 3) == 0 && (gn + r) < NN)
          hout[(gn + r) * 16 + 4 * nt + (m >> 2)] = pack4_fp8(v, p1, p2, p3);
      }
    }
  }
}

// ---------------- fused dispatch: bucketA ∥ gemm1 (grid concatenation) ----------------
__global__ __launch_bounds__(256) void buildA_gemm1_kernel(
    const int* __restrict__ EI, unsigned* __restrict__ bucketed, int* __restrict__ gcur,
    const float* __restrict__ X, const float* __restrict__ W,
    const float* __restrict__ As, const float* __restrict__ Ad,
    unsigned* __restrict__ hout, float* __restrict__ es, float* __restrict__ ed) {
  __shared__ __align__(16) char smem[32768];
  if (blockIdx.x < ABLOCKS)
    bucketA_body(blockIdx.x, EI, bucketed, gcur, smem);
  else
    gemm1_body(blockIdx.x - ABLOCKS, X, W, As, Ad, hout, es, ed, smem);
}

// ---------------- bucketB: 1024 threads (4x latency hiding), inline scan ----------------
__global__ __launch_bounds__(1024) void bucketB_kernel(
    const unsigned* __restrict__ bucketed, const int* __restrict__ gcur,
    int* __restrict__ rowptr, int* __restrict__ csr) {
  __shared__ int sc[256];
  __shared__ int hist[512];
  __shared__ int cur[512];
  __shared__ int ssum[256];
  const int t = threadIdx.x;
  const int b = blockIdx.x;
  if (t < 256) sc[t] = (t < NBKT) ? gcur[t] : 0;
  __syncthreads();
  for (int off = 1; off < 256; off <<= 1) {
    int add = (t >= off && t < 256) ? sc[t - off] : 0;
    __syncthreads();
    if (t < 256) sc[t] += add;
    __syncthreads();
  }
  const int cnt = gcur[b];
  const int base = sc[b] - cnt;
  if (b == 0 && t == 0) rowptr[NN] = ETOT;
  const unsigned* bp = bucketed + (long long)b * BCAP;
  if (t < 512) hist[t] = 0;
  __syncthreads();
  for (int i = t; i < cnt; i += 1024) atomicAdd(&hist[bp[i] & 511], 1);
  __syncthreads();
  int a0 = 0, a1 = 0, s = 0;
  if (t < 256) {
    a0 = hist[2 * t];
    a1 = hist[2 * t + 1];
    s = a0 + a1;
    ssum[t] = s;
  }
  __syncthreads();
  for (int off = 1; off < 256; off <<= 1) {
    int add = (t >= off && t < 256) ? ssum[t - off] : 0;
    __syncthreads();
    if (t < 256) ssum[t] += add;
    __syncthreads();
  }
  if (t < 256) {
    int ex = ssum[t] - s;
    cur[2 * t] = ex;
    cur[2 * t + 1] = ex + a0;
    int gn = b * 512 + 2 * t;
    if (gn < NN) rowptr[gn] = base + ex;
    if (gn + 1 < NN) rowptr[gn + 1] = base + ex + a0;
  }
  __syncthreads();
  for (int i = t; i < cnt; i += 1024) {
    unsigned e = bp[i];
    int pos = atomicAdd(&cur[e & 511], 1);
    csr[base + pos] = (int)(e >> 9);
  }
}

// ---------------- fused: aggregate layer L -> LDS -> gemm layer L+1 ----------------
// ROUND-22: 4-lane-per-node aggregation (see aggregate_node). 256 threads
// cover all 64 nodes at once (sequential half-loop removed).
__global__ __launch_bounds__(256) void agg_gemm_kernel(
    const int* __restrict__ rowptr, const int* __restrict__ csr,
    const float* __restrict__ esIn, const float* __restrict__ edIn,
    const uint4* __restrict__ h16In, const float* __restrict__ biasA,
    const float* __restrict__ W, const float* __restrict__ As,
    const float* __restrict__ Ad,
    unsigned* __restrict__ hOut, float* __restrict__ esOut, float* __restrict__ edOut) {
  constexpr int K = HD, RW = K / 2;   // 64, 32
  __shared__ unsigned Xw[64 * RW];
  __shared__ unsigned Ww[64 * RW];
  const int t = threadIdx.x;
  const int nodeBase = blockIdx.x * 64;

  for (int i4 = t * 4; i4 < 64 * K; i4 += 1024) {
    int f = i4 >> 6, k = i4 & (K - 1);
    float4 v = *(const float4*)(W + ((long long)f << 6) + k);
    uint2 p = make_uint2(pk2(v.x, v.y), pk2(v.z, v.w));
    int kw = k >> 1;
    *(uint2*)&Ww[f * RW + (kw ^ ((f & 7) << 2))] = p;
  }

  const int fl = t & 3;
  const int nl = t >> 2;              // 0..63
  const int n = nodeBase + nl;
  const int sxa = (nl & 7) << 2;
  const int wb0 = nl * RW + ((fl * 8) ^ sxa);
  const int wb1 = nl * RW + ((fl * 8 + 4) ^ sxa);
  if (n < NN) {
    float acc[16];
    const float inv = aggregate_node(n, fl, rowptr, csr, esIn, edIn, h16In, acc);
    float v[16];
#pragma unroll
    for (int j = 0; j < 16; j++)
      v[j] = fmaxf(acc[j] * inv + biasA[16 * fl + j], 0.f);   // relu (layers 1,2)
    uint4 pa, pb;
    pa.x = pk2(v[0], v[1]);   pa.y = pk2(v[2], v[3]);
    pa.z = pk2(v[4], v[5]);   pa.w = pk2(v[6], v[7]);
    pb.x = pk2(v[8], v[9]);   pb.y = pk2(v[10], v[11]);
    pb.z = pk2(v[12], v[13]); pb.w = pk2(v[14], v[15]);
    *(uint4*)&Xw[wb0] = pa;
    *(uint4*)&Xw[wb1] = pb;
  } else {
    *(uint4*)&Xw[wb0] = make_uint4(0u, 0u, 0u, 0u);
    *(uint4*)&Xw[wb1] = make_uint4(0u, 0u, 0u, 0u);
  }
  __syncthreads();

  const int w = t >> 6, l = t & 63, m = l & 15, q = l >> 4;
  const int nodeLoc = 16 * w + m;
  const int sxb = (nodeLoc & 7) << 2;
  floatx4 acc[4];
#pragma unroll
  for (int nt = 0; nt < 4; nt++) acc[nt] = (floatx4){0.f, 0.f, 0.f, 0.f};
#pragma unroll
  for (int kc = 0; kc < K; kc += 32) {
    const int kcw = (kc >> 1) + 4 * q;
    short8 af = *(const short8*)&Xw[nodeLoc * RW + (kcw ^ sxb)];
#pragma unroll
    for (int nt = 0; nt < 4; nt++) {
      int f = 16 * nt + m;
      short8 bf = *(const short8*)&Ww[f * RW + (kcw ^ ((f & 7) << 2))];
      acc[nt] = __builtin_amdgcn_mfma_f32_16x16x32_bf16(af, bf, acc[nt], 0, 0, 0);
    }
  }
  float asv[4], adv[4];
#pragma unroll
  for (int nt = 0; nt < 4; nt++) { asv[nt] = As[16 * nt + m]; adv[nt] = Ad[16 * nt + m]; }
#pragma unroll
  for (int r = 0; r < 4; r++) {
    float ss = 0.f, sd2 = 0.f;
#pragma unroll
    for (int nt = 0; nt < 4; nt++) {
      ss = fmaf(acc[nt][r], asv[nt], ss);
      sd2 = fmaf(acc[nt][r], adv[nt], sd2);
    }
#pragma unroll
    for (int off = 1; off < 16; off <<= 1) {
      ss += __shfl_xor(ss, off);
      sd2 += __shfl_xor(sd2, off);
    }
    if (m == 0) {
      int gn = nodeBase + 16 * w + 4 * q + r;
      if (gn < NN) { esOut[gn] = ss * LOG2E; edOut[gn] = sd2 * LOG2E; }
    }
  }
  {
    int gn = nodeBase + 16 * w + 4 * q;
#pragma unroll
    for (int nt = 0; nt < 4; nt++) {
#pragma unroll
      for (int r = 0; r < 4; r++) {
        float v = acc[nt][r];
        float p1 = __shfl_xor(v, 1);
        float p2 = __shfl_xor(v, 2);
        float p3 = __shfl_xor(v, 3);
        if ((m & 3) == 0 && (gn + r) < NN)
          hOut[(gn + r) * 16 + 4 * nt + (m >> 2)] = pack4_fp8(v, p1, p2, p3);
      }
    }
  }
}

// ---------------- fused: aggregate layer 3 + mean-pool scatter ----------------
// ROUND-22: same 4-lane-per-node structure; 64 nodes/block, grid GBLOCKS.
__global__ __launch_bounds__(256) void agg3_pool_kernel(
    const int* __restrict__ rowptr, const int* __restrict__ csr,
    const float* __restrict__ esIn, const float* __restrict__ edIn,
    const uint4* __restrict__ h16In, const float* __restrict__ biasA,
    const int* __restrict__ batch, float* __restrict__ pooled) {
  __shared__ float P[64 * 66];
  __shared__ int gl[64];
  const int t = threadIdx.x;
  const int fl = t & 3;
  const int nl = t >> 2;               // 0..63
  const int n = blockIdx.x * 64 + nl;
  if (t < 64) {
    int bn = blockIdx.x * 64 + t;
    gl[t] = batch[(bn < NN) ? bn : (NN - 1)];
  }
  if (n < NN) {
    float acc[16];
    const float inv = aggregate_node(n, fl, rowptr, csr, esIn, edIn, h16In, acc);
#pragma unroll
    for (int j = 0; j < 16; j++)
      P[nl * 66 + 16 * fl + j] = acc[j] * inv + biasA[16 * fl + j];  // no relu (layer 3)
  } else {
#pragma unroll
    for (int j = 0; j < 16; j++)
      P[nl * 66 + 16 * fl + j] = 0.f;
  }
  __syncthreads();
  if (t < HD) {
    const int f = t;
    float s = 0.f;
    int gcur = gl[0];
    for (int k = 0; k < 64; k++) {
      int g = gl[k];
      if (g != gcur) {
        atomicAdd(&pooled[gcur * HD + f], s);
        s = 0.f;
        gcur = g;
      }
      s += P[k * 66 + f];
    }
    atomicAdd(&pooled[gcur * HD + f], s);
  }
}

// ---------------- final linear ----------------
__device__ __forceinline__ int lower_bound_batch(const int* bt, int target) {
  int lo = 0, hi = NN;
  while (lo < hi) {
    int mid = (lo + hi) >> 1;
    if (bt[mid] < target) lo = mid + 1; else hi = mid;
  }
  return lo;
}

__global__ void final_kernel(
    const float* __restrict__ pooled, const int* __restrict__ batch,
    const float* __restrict__ Wlin, const float* __restrict__ blin,
    float* __restrict__ out) {
  int t = blockIdx.x * blockDim.x + threadIdx.x;
  if (t >= NB * NC) return;
  int b = t / NC, c = t - b * NC;
  int lo = lower_bound_batch(batch, b);
  int hi = lower_bound_batch(batch, b + 1);
  float inv = 1.0f / fmaxf((float)(hi - lo), 1.0f);
  float a = blin[c];
#pragma unroll 16
  for (int f = 0; f < HD; f++)
    a = fmaf(pooled[b * HD + f] * inv, Wlin[(long long)c * HD + f], a);
  out[t] = a;
}

extern "C" void kernel_launch(void* const* d_in, const int* in_sizes, int n_in,
                              void* d_out, int out_size, void* d_ws, size_t ws_size,
                              hipStream_t stream) {
  char* ws = (char*)d_ws;
  unsigned* hA       = (unsigned*)(ws + OFF_HA);
  unsigned* hB       = (unsigned*)(ws + OFF_HB);
  float*    esA      = (float*)(ws + OFF_ESA);
  float*    edA      = (float*)(ws + OFF_EDA);
  float*    esB      = (float*)(ws + OFF_ESB);
  float*    edB      = (float*)(ws + OFF_EDB);
  int*      rowptr   = (int*)(ws + OFF_ROW);
  int*      csr      = (int*)(ws + OFF_CSR);
  int*      gcur     = (int*)(ws + OFF_GC);
  float*    pooled   = (float*)(ws + OFF_POOL);
  unsigned* bucketed = (unsigned*)(ws + OFF_BKT);

  const float* X  = (const float*)d_in[0];
  const int*   EI = (const int*)d_in[1];     // int32
  const int*   BT = (const int*)d_in[2];     // int32
  const float* Wm[3] = {(const float*)d_in[3], (const float*)d_in[7], (const float*)d_in[11]};
  const float* As[3] = {(const float*)d_in[4], (const float*)d_in[8], (const float*)d_in[12]};
  const float* Ad[3] = {(const float*)d_in[5], (const float*)d_in[9], (const float*)d_in[13]};
  const float* Bb[3] = {(const float*)d_in[6], (const float*)d_in[10], (const float*)d_in[14]};
  const float* Wl = (const float*)d_in[15];
  const float* bl = (const float*)d_in[16];

  (void)hipMemsetAsync(gcur, 0, 1024 + (size_t)NB * HD * 4, stream);
  buildA_gemm1_kernel<<<ABLOCKS + GBLOCKS, 256, 0, stream>>>(
      EI, bucketed, gcur, X, Wm[0], As[0], Ad[0], hA, esA, edA);
  bucketB_kernel<<<NBKT, 1024, 0, stream>>>(bucketed, gcur, rowptr, csr);
  agg_gemm_kernel<<<GBLOCKS, 256, 0, stream>>>(
      rowptr, csr, esA, edA, (const uint4*)hA, Bb[0],
      Wm[1], As[1], Ad[1], hB, esB, edB);
  agg_gemm_kernel<<<GBLOCKS, 256, 0, stream>>>(
      rowptr, csr, esB, edB, (const uint4*)hB, Bb[1],
      Wm[2], As[2], Ad[2], hA, esA, edA);
  agg3_pool_kernel<<<GBLOCKS, 256, 0, stream>>>(
      rowptr, csr, esA, edA, (const uint4*)hA, Bb[2], BT, pooled);
  final_kernel<<<(NB * NC + 255) / 256, 256, 0, stream>>>(pooled, BT, Wl, bl, (float*)d_out);
}

// Round 3
// 275.058 us; speedup vs baseline: 1.0409x; 1.0409x over previous
//
#include <hip/hip_runtime.h>
#include <hip/hip_bf16.h>

#define NN 100000
#define EE 1600000
#define ETOT 1700000   // EE + NN self loops
#define FIN1 128
#define HD 64
#define NC 10
#define NB 128
#define NEG 0.2f
#define LOG2E 1.44269504f

#define NBKT 196       // ceil(NN/512)
#define BCAP 10240     // per-bucket capacity (mean 8673, sd ~93)
#define BLKE 4096      // edges per bucketA block (round-19 2048 regressed: fragmentation)
#define ABLOCKS ((ETOT + BLKE - 1) / BLKE)   // 416
#define GBLOCKS ((NN + 63) / 64)             // 1563

// Input dtypes: floats fp32, integers int32 (harness spec; round-16 verified).

// workspace layout (bytes)
static constexpr size_t OFF_HA   = 0;                                // 6.4 MB
static constexpr size_t OFF_HB   = (size_t)NN * HD;                  // 6.4 MB
static constexpr size_t OFF_ESA  = (size_t)NN * HD * 2;
static constexpr size_t OFF_EDA  = OFF_ESA + (size_t)NN * 4;
static constexpr size_t OFF_ESB  = OFF_EDA + (size_t)NN * 4;
static constexpr size_t OFF_EDB  = OFF_ESB + (size_t)NN * 4;
static constexpr size_t OFF_ROW  = OFF_EDB + (size_t)NN * 4;         // rowptr[NN+1]
static constexpr size_t OFF_CSR  = OFF_ROW + (size_t)(NN + 4) * 4;   // 6.8 MB
static constexpr size_t OFF_GC   = OFF_CSR + (size_t)ETOT * 4;       // 1024 B
static constexpr size_t OFF_POOL = OFF_GC + 1024;                    // 32 KB (gcur+pooled: one memset)
static constexpr size_t OFF_BKT  = OFF_POOL + (size_t)NB * HD * 4;   // 8.03 MB
// total ~29.8 MB

typedef __attribute__((ext_vector_type(8))) short short8;   // 8 bf16 = 4 VGPR
typedef __attribute__((ext_vector_type(4))) float floatx4;
typedef __attribute__((ext_vector_type(2))) float floatx2;

__device__ __forceinline__ unsigned short f2bf(float f) {
  unsigned u = __float_as_uint(f);
  if ((u & 0x7F800000u) == 0x7F800000u) return (unsigned short)(u >> 16);
  return (unsigned short)((u + 0x7FFFu + ((u >> 16) & 1u)) >> 16);
}
__device__ __forceinline__ unsigned pk2(float a, float b) {
  return (unsigned)f2bf(a) | ((unsigned)f2bf(b) << 16);
}

// ---- fp8 e4m3 pack/unpack (HW builtins on gfx950; manual fallback) ----
#if __has_builtin(__builtin_amdgcn_cvt_pk_fp8_f32) && __has_builtin(__builtin_amdgcn_cvt_pk_f32_fp8)
#define HW_FP8 1
#endif
__device__ __forceinline__ unsigned enc1_fp8(float f) {
  _Float16 hf = (_Float16)f;
  unsigned short b = __builtin_bit_cast(unsigned short, hf);
  unsigned s = ((unsigned)b >> 8) & 0x80u;
  int mag = b & 0x7fff;
  if (mag < 0x2380) return s;
  int r = mag + 0x3F + ((mag >> 7) & 1);
  int m = (r >> 7) - 64;
  if (m > 0x7E) m = 0x7E;
  return s | (unsigned)m;
}
__device__ __forceinline__ unsigned pack4_fp8(float a, float b, float c, float d) {
#ifdef HW_FP8
  int w = __builtin_amdgcn_cvt_pk_fp8_f32(a, b, 0, false);
  w = __builtin_amdgcn_cvt_pk_fp8_f32(c, d, w, true);
  return (unsigned)w;
#else
  return enc1_fp8(a) | (enc1_fp8(b) << 8) | (enc1_fp8(c) << 16) | (enc1_fp8(d) << 24);
#endif
}
__device__ __forceinline__ float dec1_fp8(unsigned byte) {
  unsigned short hb = (unsigned short)(((byte & 0x80u) << 8) | ((byte & 0x7fu) << 7));
  _Float16 hf = __builtin_bit_cast(_Float16, hb);
  return (float)hf * 256.0f;
}
template <bool HI>
__device__ __forceinline__ floatx2 unpk2_fp8(unsigned w) {
#ifdef HW_FP8
  return __builtin_amdgcn_cvt_pk_f32_fp8((int)w, HI);
#else
  unsigned s = HI ? (w >> 16) : w;
  floatx2 r; r.x = dec1_fp8(s & 0xffu); r.y = dec1_fp8((s >> 8) & 0xffu);
  return r;
#endif
}

// 16-feature fp8 accumulate: acc[j] += w * feature[j]
__device__ __forceinline__ void acc16(float* acc, float w, uint4 u) {
  floatx2 f0 = unpk2_fp8<false>(u.x), f1 = unpk2_fp8<true>(u.x);
  floatx2 f2 = unpk2_fp8<false>(u.y), f3 = unpk2_fp8<true>(u.y);
  floatx2 f4 = unpk2_fp8<false>(u.z), f5 = unpk2_fp8<true>(u.z);
  floatx2 f6 = unpk2_fp8<false>(u.w), f7 = unpk2_fp8<true>(u.w);
  acc[0]  = fmaf(w, f0.x, acc[0]);  acc[1]  = fmaf(w, f0.y, acc[1]);
  acc[2]  = fmaf(w, f1.x, acc[2]);  acc[3]  = fmaf(w, f1.y, acc[3]);
  acc[4]  = fmaf(w, f2.x, acc[4]);  acc[5]  = fmaf(w, f2.y, acc[5]);
  acc[6]  = fmaf(w, f3.x, acc[6]);  acc[7]  = fmaf(w, f3.y, acc[7]);
  acc[8]  = fmaf(w, f4.x, acc[8]);  acc[9]  = fmaf(w, f4.y, acc[9]);
  acc[10] = fmaf(w, f5.x, acc[10]); acc[11] = fmaf(w, f5.y, acc[11]);
  acc[12] = fmaf(w, f6.x, acc[12]); acc[13] = fmaf(w, f6.y, acc[13]);
  acc[14] = fmaf(w, f7.x, acc[14]); acc[15] = fmaf(w, f7.y, acc[15]);
}

// ROUND-23: 4-lane-per-node aggregation with SOFTWARE-PIPELINED h-gather.
// Round-22 post-mortem: 3 structurally different loops all land 47-53 us
// (VALU halved -> flat; lane-reqs/edge cut 3x -> flat; HBM 18% of peak).
// Remaining wall: h-gather latency exposed EVERY iteration (issue+consume in
// same iter; csr/es were prefetched, h was not). This version: h gathers for
// iter i+1 issued during iter i (csr/es prefetched two-deep to feed them);
// acc16 of iter i runs on registers in flight since iter i-1. Same request
// count, same bytes - pure latency-exposure experiment.
__device__ __forceinline__ float aggregate_node(
    int n, int fl, const int* __restrict__ rowptr, const int* __restrict__ csr,
    const float* __restrict__ esIn, const float* __restrict__ edIn,
    const uint4* __restrict__ h16, float* acc) {
#pragma unroll
  for (int j = 0; j < 16; j++) acc[j] = 0.f;
  const float edn = edIn[n];
  const int row = rowptr[n];
  const int end = rowptr[n + 1];
  const int endm1 = end - 1;
  float den = 0.f;

  // prologue: iter-0 and iter-1 csr/es, iter-0 h in flight
  int i0 = row + fl;
  int sA = csr[(i0 < end) ? i0 : endm1];          // iter 0 (my edge)
  float evA = esIn[sA];
  int sB = sA;
  if (row + 4 < end) {
    int i1 = row + 4 + fl;
    sB = csr[(i1 < end) ? i1 : endm1];            // iter 1
  }
  float evB = esIn[sB];
  int a0 = __shfl(sA, 0, 4), a1 = __shfl(sA, 1, 4);
  int a2 = __shfl(sA, 2, 4), a3 = __shfl(sA, 3, 4);
  uint4 uA0 = h16[a0 * 4 + fl];
  uint4 uA1 = h16[a1 * 4 + fl];
  uint4 uA2 = h16[a2 * 4 + fl];
  uint4 uA3 = h16[a3 * 4 + fl];

  for (int i = row; i < end; i += 4) {
    // prefetch csr/es two iterations ahead (feeds next iter's h issue)
    int sC = sB;
    if (i + 8 < end) {
      int ip = i + 8 + fl;
      sC = csr[(ip < end) ? ip : endm1];
    }
    float evC = esIn[sC];
    // issue h-gather for iter i+4 (consumed next iteration)
    int b0 = __shfl(sB, 0, 4), b1 = __shfl(sB, 1, 4);
    int b2 = __shfl(sB, 2, 4), b3 = __shfl(sB, 3, 4);
    uint4 uB0 = h16[b0 * 4 + fl];
    uint4 uB1 = h16[b1 * 4 + fl];
    uint4 uB2 = h16[b2 * 4 + fl];
    uint4 uB3 = h16[b3 * 4 + fl];
    // weight for MY edge of iter i (1 leaky+exp2 per edge)
    float e = evA + edn;
    e = fmaxf(e, NEG * e);
    float w = exp2f(e);
    w = (i + fl < end) ? w : 0.f;
    den += w;
    float w0 = __shfl(w, 0, 4), w1 = __shfl(w, 1, 4);
    float w2 = __shfl(w, 2, 4), w3 = __shfl(w, 3, 4);
    // consume iter-i h (in flight since previous iteration)
    acc16(acc, w0, uA0);
    acc16(acc, w1, uA1);
    acc16(acc, w2, uA2);
    acc16(acc, w3, uA3);
    // rotate pipeline registers
    uA0 = uB0; uA1 = uB1; uA2 = uB2; uA3 = uB3;
    evA = evB; evB = evC;
    sB = sC;
  }
  den += __shfl_xor(den, 1, 4);
  den += __shfl_xor(den, 2, 4);
  return 1.0f / den;
}

// ---------------- bucketA body: LDS-staged, bucket-sorted COALESCED writes ----------------
__device__ __forceinline__ void bucketA_body(
    int bid, const int* __restrict__ EI, unsigned* __restrict__ bucketed,
    int* __restrict__ gcur, char* smem) {
  unsigned* stage = (unsigned*)smem;                        // BLKE words   16 KB
  unsigned short* sb = (unsigned short*)(smem + BLKE * 4);  // BLKE shorts   8 KB
  int* cnt  = (int*)(smem + BLKE * 4 + BLKE * 2);           // NBKT
  int* lofs = cnt + NBKT;                                   // NBKT
  int* base = lofs + NBKT;                                  // NBKT
  int* sc   = base + NBKT;                                  // 256
  const int t = threadIdx.x;
  const long long start = (long long)bid * BLKE;
  long long rem = (long long)ETOT - start;
  const int V = (rem < BLKE) ? (int)rem : BLKE;
  unsigned pk[BLKE / 256];
  short bk[BLKE / 256];
  for (int i = t; i < NBKT; i += 256) cnt[i] = 0;
  __syncthreads();
#pragma unroll
  for (int j = 0; j < BLKE / 256; j++) {
    long long k = start + t + 256 * j;
    bk[j] = -1;
    if (k < ETOT) {
      int s, d;
      if (k < EE) { s = EI[k]; d = EI[(long long)EE + k]; }
      else        { s = d = (int)(k - EE); }
      int b = d >> 9;
      pk[j] = ((unsigned)s << 9) | (unsigned)(d & 511);
      bk[j] = (short)b;
      atomicAdd(&cnt[b], 1);
    }
  }
  __syncthreads();
  // exclusive scan of cnt -> lofs; reserve global space; reset cnt as cursor
  int own = (t < NBKT) ? cnt[t] : 0;
  sc[t] = own;
  __syncthreads();
  for (int off = 1; off < 256; off <<= 1) {
    int add = (t >= off) ? sc[t - off] : 0;
    __syncthreads();
    sc[t] += add;
    __syncthreads();
  }
  if (t < NBKT) {
    lofs[t] = sc[t] - own;
    base[t] = (own > 0) ? atomicAdd(&gcur[t], own) : 0;
    cnt[t] = 0;
  }
  __syncthreads();
  // scatter into LDS staging (sorted by bucket)
#pragma unroll
  for (int j = 0; j < BLKE / 256; j++) {
    if (bk[j] >= 0) {
      int b = bk[j];
      int p = lofs[b] + atomicAdd(&cnt[b], 1);
      stage[p] = pk[j];
      sb[p] = (unsigned short)b;
    }
  }
  __syncthreads();
  // coalesced copy-out: entry i -> bucketed[b*BCAP + base[b] + (i - lofs[b])]
  for (int i = t; i < V; i += 256) {
    int b = sb[i];
    int pos = base[b] + (i - lofs[b]);
    if (pos < BCAP) bucketed[(long long)b * BCAP + pos] = stage[i];
  }
}

// ---------------- gemm1 body: h1 = x@W1^T from fp32 input (MFMA) ----------------
__device__ __forceinline__ void gemm1_body(
    int bid, const float* __restrict__ X, const float* __restrict__ W,
    const float* __restrict__ As, const float* __restrict__ Ad,
    unsigned* __restrict__ hout, float* __restrict__ es, float* __restrict__ ed,
    char* smem) {
  constexpr int K = FIN1, RW = K / 2;
  unsigned* Xw = (unsigned*)smem;             // 16 KB
  unsigned* Ww = (unsigned*)(smem + 16384);   // 16 KB
  const int t = threadIdx.x;
  const int nodeBase = bid * 64;

  for (int i4 = t * 4; i4 < 64 * K; i4 += 1024) {
    int node = i4 >> 7, k = i4 & (K - 1);
    float4 v = make_float4(0.f, 0.f, 0.f, 0.f);
    if (nodeBase + node < NN)
      v = *(const float4*)(X + ((long long)(nodeBase + node) << 7) + k);
    uint2 p = make_uint2(pk2(v.x, v.y), pk2(v.z, v.w));
    int kw = k >> 1;
    *(uint2*)&Xw[node * RW + (kw ^ ((node & 7) << 2))] = p;
  }
  for (int i4 = t * 4; i4 < 64 * K; i4 += 1024) {
    int f = i4 >> 7, k = i4 & (K - 1);
    float4 v = *(const float4*)(W + ((long long)f << 7) + k);
    uint2 p = make_uint2(pk2(v.x, v.y), pk2(v.z, v.w));
    int kw = k >> 1;
    *(uint2*)&Ww[f * RW + (kw ^ ((f & 7) << 2))] = p;
  }
  __syncthreads();

  const int w = t >> 6, l = t & 63, m = l & 15, q = l >> 4;
  const int nodeLoc = 16 * w + m;
  const int sxa = (nodeLoc & 7) << 2;
  floatx4 acc[4];
#pragma unroll
  for (int nt = 0; nt < 4; nt++) acc[nt] = (floatx4){0.f, 0.f, 0.f, 0.f};
#pragma unroll
  for (int kc = 0; kc < K; kc += 32) {
    const int kcw = (kc >> 1) + 4 * q;
    short8 af = *(const short8*)&Xw[nodeLoc * RW + (kcw ^ sxa)];
#pragma unroll
    for (int nt = 0; nt < 4; nt++) {
      int f = 16 * nt + m;
      short8 bf = *(const short8*)&Ww[f * RW + (kcw ^ ((f & 7) << 2))];
      acc[nt] = __builtin_amdgcn_mfma_f32_16x16x32_bf16(af, bf, acc[nt], 0, 0, 0);
    }
  }
  float asv[4], adv[4];
#pragma unroll
  for (int nt = 0; nt < 4; nt++) { asv[nt] = As[16 * nt + m]; adv[nt] = Ad[16 * nt + m]; }
#pragma unroll
  for (int r = 0; r < 4; r++) {
    float ss = 0.f, sd2 = 0.f;
#pragma unroll
    for (int nt = 0; nt < 4; nt++) {
      ss = fmaf(acc[nt][r], asv[nt], ss);
      sd2 = fmaf(acc[nt][r], adv[nt], sd2);
    }
#pragma unroll
    for (int off = 1; off < 16; off <<= 1) {
      ss += __shfl_xor(ss, off);
      sd2 += __shfl_xor(sd2, off);
    }
    if (m == 0) {
      int gn = nodeBase + 16 * w + 4 * q + r;
      if (gn < NN) { es[gn] = ss * LOG2E; ed[gn] = sd2 * LOG2E; }
    }
  }
  {
    int gn = nodeBase + 16 * w + 4 * q;
#pragma unroll
    for (int nt = 0; nt < 4; nt++) {
#pragma unroll
      for (int r = 0; r < 4; r++) {
        float v = acc[nt][r];
        float p1 = __shfl_xor(v, 1);
        float p2 = __shfl_xor(v, 2);
        float p3 = __shfl_xor(v, 3);
        if ((m & 3) == 0 && (gn + r) < NN)
          hout[(gn + r) * 16 + 4 * nt + (m >> 2)] = pack4_fp8(v, p1, p2, p3);
      }
    }
  }
}

// ---------------- fused dispatch: bucketA ∥ gemm1 (grid concatenation) ----------------
__global__ __launch_bounds__(256) void buildA_gemm1_kernel(
    const int* __restrict__ EI, unsigned* __restrict__ bucketed, int* __restrict__ gcur,
    const float* __restrict__ X, const float* __restrict__ W,
    const float* __restrict__ As, const float* __restrict__ Ad,
    unsigned* __restrict__ hout, float* __restrict__ es, float* __restrict__ ed) {
  __shared__ __align__(16) char smem[32768];
  if (blockIdx.x < ABLOCKS)
    bucketA_body(blockIdx.x, EI, bucketed, gcur, smem);
  else
    gemm1_body(blockIdx.x - ABLOCKS, X, W, As, Ad, hout, es, ed, smem);
}

// ---------------- bucketB: 1024 threads (4x latency hiding), inline scan ----------------
__global__ __launch_bounds__(1024) void bucketB_kernel(
    const unsigned* __restrict__ bucketed, const int* __restrict__ gcur,
    int* __restrict__ rowptr, int* __restrict__ csr) {
  __shared__ int sc[256];
  __shared__ int hist[512];
  __shared__ int cur[512];
  __shared__ int ssum[256];
  const int t = threadIdx.x;
  const int b = blockIdx.x;
  if (t < 256) sc[t] = (t < NBKT) ? gcur[t] : 0;
  __syncthreads();
  for (int off = 1; off < 256; off <<= 1) {
    int add = (t >= off && t < 256) ? sc[t - off] : 0;
    __syncthreads();
    if (t < 256) sc[t] += add;
    __syncthreads();
  }
  const int cnt = gcur[b];
  const int base = sc[b] - cnt;
  if (b == 0 && t == 0) rowptr[NN] = ETOT;
  const unsigned* bp = bucketed + (long long)b * BCAP;
  if (t < 512) hist[t] = 0;
  __syncthreads();
  for (int i = t; i < cnt; i += 1024) atomicAdd(&hist[bp[i] & 511], 1);
  __syncthreads();
  int a0 = 0, a1 = 0, s = 0;
  if (t < 256) {
    a0 = hist[2 * t];
    a1 = hist[2 * t + 1];
    s = a0 + a1;
    ssum[t] = s;
  }
  __syncthreads();
  for (int off = 1; off < 256; off <<= 1) {
    int add = (t >= off && t < 256) ? ssum[t - off] : 0;
    __syncthreads();
    if (t < 256) ssum[t] += add;
    __syncthreads();
  }
  if (t < 256) {
    int ex = ssum[t] - s;
    cur[2 * t] = ex;
    cur[2 * t + 1] = ex + a0;
    int gn = b * 512 + 2 * t;
    if (gn < NN) rowptr[gn] = base + ex;
    if (gn + 1 < NN) rowptr[gn + 1] = base + ex + a0;
  }
  __syncthreads();
  for (int i = t; i < cnt; i += 1024) {
    unsigned e = bp[i];
    int pos = atomicAdd(&cur[e & 511], 1);
    csr[base + pos] = (int)(e >> 9);
  }
}

// ---------------- fused: aggregate layer L -> LDS -> gemm layer L+1 ----------------
__global__ __launch_bounds__(256) void agg_gemm_kernel(
    const int* __restrict__ rowptr, const int* __restrict__ csr,
    const float* __restrict__ esIn, const float* __restrict__ edIn,
    const uint4* __restrict__ h16In, const float* __restrict__ biasA,
    const float* __restrict__ W, const float* __restrict__ As,
    const float* __restrict__ Ad,
    unsigned* __restrict__ hOut, float* __restrict__ esOut, float* __restrict__ edOut) {
  constexpr int K = HD, RW = K / 2;   // 64, 32
  __shared__ unsigned Xw[64 * RW];
  __shared__ unsigned Ww[64 * RW];
  const int t = threadIdx.x;
  const int nodeBase = blockIdx.x * 64;

  for (int i4 = t * 4; i4 < 64 * K; i4 += 1024) {
    int f = i4 >> 6, k = i4 & (K - 1);
    float4 v = *(const float4*)(W + ((long long)f << 6) + k);
    uint2 p = make_uint2(pk2(v.x, v.y), pk2(v.z, v.w));
    int kw = k >> 1;
    *(uint2*)&Ww[f * RW + (kw ^ ((f & 7) << 2))] = p;
  }

  const int fl = t & 3;
  const int nl = t >> 2;              // 0..63
  const int n = nodeBase + nl;
  const int sxa = (nl & 7) << 2;
  const int wb0 = nl * RW + ((fl * 8) ^ sxa);
  const int wb1 = nl * RW + ((fl * 8 + 4) ^ sxa);
  if (n < NN) {
    float acc[16];
    const float inv = aggregate_node(n, fl, rowptr, csr, esIn, edIn, h16In, acc);
    float v[16];
#pragma unroll
    for (int j = 0; j < 16; j++)
      v[j] = fmaxf(acc[j] * inv + biasA[16 * fl + j], 0.f);   // relu (layers 1,2)
    uint4 pa, pb;
    pa.x = pk2(v[0], v[1]);   pa.y = pk2(v[2], v[3]);
    pa.z = pk2(v[4], v[5]);   pa.w = pk2(v[6], v[7]);
    pb.x = pk2(v[8], v[9]);   pb.y = pk2(v[10], v[11]);
    pb.z = pk2(v[12], v[13]); pb.w = pk2(v[14], v[15]);
    *(uint4*)&Xw[wb0] = pa;
    *(uint4*)&Xw[wb1] = pb;
  } else {
    *(uint4*)&Xw[wb0] = make_uint4(0u, 0u, 0u, 0u);
    *(uint4*)&Xw[wb1] = make_uint4(0u, 0u, 0u, 0u);
  }
  __syncthreads();

  const int w = t >> 6, l = t & 63, m = l & 15, q = l >> 4;
  const int nodeLoc = 16 * w + m;
  const int sxb = (nodeLoc & 7) << 2;
  floatx4 acc[4];
#pragma unroll
  for (int nt = 0; nt < 4; nt++) acc[nt] = (floatx4){0.f, 0.f, 0.f, 0.f};
#pragma unroll
  for (int kc = 0; kc < K; kc += 32) {
    const int kcw = (kc >> 1) + 4 * q;
    short8 af = *(const short8*)&Xw[nodeLoc * RW + (kcw ^ sxb)];
#pragma unroll
    for (int nt = 0; nt < 4; nt++) {
      int f = 16 * nt + m;
      short8 bf = *(const short8*)&Ww[f * RW + (kcw ^ ((f & 7) << 2))];
      acc[nt] = __builtin_amdgcn_mfma_f32_16x16x32_bf16(af, bf, acc[nt], 0, 0, 0);
    }
  }
  float asv[4], adv[4];
#pragma unroll
  for (int nt = 0; nt < 4; nt++) { asv[nt] = As[16 * nt + m]; adv[nt] = Ad[16 * nt + m]; }
#pragma unroll
  for (int r = 0; r < 4; r++) {
    float ss = 0.f, sd2 = 0.f;
#pragma unroll
    for (int nt = 0; nt < 4; nt++) {
      ss = fmaf(acc[nt][r], asv[nt], ss);
      sd2 = fmaf(acc[nt][r], adv[nt], sd2);
    }
#pragma unroll
    for (int off = 1; off < 16; off <<= 1) {
      ss += __shfl_xor(ss, off);
      sd2 += __shfl_xor(sd2, off);
    }
    if (m == 0) {
      int gn = nodeBase + 16 * w + 4 * q + r;
      if (gn < NN) { esOut[gn] = ss * LOG2E; edOut[gn] = sd2 * LOG2E; }
    }
  }
  {
    int gn = nodeBase + 16 * w + 4 * q;
#pragma unroll
    for (int nt = 0; nt < 4; nt++) {
#pragma unroll
      for (int r = 0; r < 4; r++) {
        float v = acc[nt][r];
        float p1 = __shfl_xor(v, 1);
        float p2 = __shfl_xor(v, 2);
        float p3 = __shfl_xor(v, 3);
        if ((m & 3) == 0 && (gn + r) < NN)
          hOut[(gn + r) * 16 + 4 * nt + (m >> 2)] = pack4_fp8(v, p1, p2, p3);
      }
    }
  }
}

// ---------------- fused: aggregate layer 3 + mean-pool scatter ----------------
__global__ __launch_bounds__(256) void agg3_pool_kernel(
    const int* __restrict__ rowptr, const int* __restrict__ csr,
    const float* __restrict__ esIn, const float* __restrict__ edIn,
    const uint4* __restrict__ h16In, const float* __restrict__ biasA,
    const int* __restrict__ batch, float* __restrict__ pooled) {
  __shared__ float P[64 * 66];
  __shared__ int gl[64];
  const int t = threadIdx.x;
  const int fl = t & 3;
  const int nl = t >> 2;               // 0..63
  const int n = blockIdx.x * 64 + nl;
  if (t < 64) {
    int bn = blockIdx.x * 64 + t;
    gl[t] = batch[(bn < NN) ? bn : (NN - 1)];
  }
  if (n < NN) {
    float acc[16];
    const float inv = aggregate_node(n, fl, rowptr, csr, esIn, edIn, h16In, acc);
#pragma unroll
    for (int j = 0; j < 16; j++)
      P[nl * 66 + 16 * fl + j] = acc[j] * inv + biasA[16 * fl + j];  // no relu (layer 3)
  } else {
#pragma unroll
    for (int j = 0; j < 16; j++)
      P[nl * 66 + 16 * fl + j] = 0.f;
  }
  __syncthreads();
  if (t < HD) {
    const int f = t;
    float s = 0.f;
    int gcur = gl[0];
    for (int k = 0; k < 64; k++) {
      int g = gl[k];
      if (g != gcur) {
        atomicAdd(&pooled[gcur * HD + f], s);
        s = 0.f;
        gcur = g;
      }
      s += P[k * 66 + f];
    }
    atomicAdd(&pooled[gcur * HD + f], s);
  }
}

// ---------------- final linear ----------------
__device__ __forceinline__ int lower_bound_batch(const int* bt, int target) {
  int lo = 0, hi = NN;
  while (lo < hi) {
    int mid = (lo + hi) >> 1;
    if (bt[mid] < target) lo = mid + 1; else hi = mid;
  }
  return lo;
}

__global__ void final_kernel(
    const float* __restrict__ pooled, const int* __restrict__ batch,
    const float* __restrict__ Wlin, const float* __restrict__ blin,
    float* __restrict__ out) {
  int t = blockIdx.x * blockDim.x + threadIdx.x;
  if (t >= NB * NC) return;
  int b = t / NC, c = t - b * NC;
  int lo = lower_bound_batch(batch, b);
  int hi = lower_bound_batch(batch, b + 1);
  float inv = 1.0f / fmaxf((float)(hi - lo), 1.0f);
  float a = blin[c];
#pragma unroll 16
  for (int f = 0; f < HD; f++)
    a = fmaf(pooled[b * HD + f] * inv, Wlin[(long long)c * HD + f], a);
  out[t] = a;
}

extern "C" void kernel_launch(void* const* d_in, const int* in_sizes, int n_in,
                              void* d_out, int out_size, void* d_ws, size_t ws_size,
                              hipStream_t stream) {
  char* ws = (char*)d_ws;
  unsigned* hA       = (unsigned*)(ws + OFF_HA);
  unsigned* hB       = (unsigned*)(ws + OFF_HB);
  float*    esA      = (float*)(ws + OFF_ESA);
  float*    edA      = (float*)(ws + OFF_EDA);
  float*    esB      = (float*)(ws + OFF_ESB);
  float*    edB      = (float*)(ws + OFF_EDB);
  int*      rowptr   = (int*)(ws + OFF_ROW);
  int*      csr      = (int*)(ws + OFF_CSR);
  int*      gcur     = (int*)(ws + OFF_GC);
  float*    pooled   = (float*)(ws + OFF_POOL);
  unsigned* bucketed = (unsigned*)(ws + OFF_BKT);

  const float* X  = (const float*)d_in[0];
  const int*   EI = (const int*)d_in[1];     // int32
  const int*   BT = (const int*)d_in[2];     // int32
  const float* Wm[3] = {(const float*)d_in[3], (const float*)d_in[7], (const float*)d_in[11]};
  const float* As[3] = {(const float*)d_in[4], (const float*)d_in[8], (const float*)d_in[12]};
  const float* Ad[3] = {(const float*)d_in[5], (const float*)d_in[9], (const float*)d_in[13]};
  const float* Bb[3] = {(const float*)d_in[6], (const float*)d_in[10], (const float*)d_in[14]};
  const float* Wl = (const float*)d_in[15];
  const float* bl = (const float*)d_in[16];

  (void)hipMemsetAsync(gcur, 0, 1024 + (size_t)NB * HD * 4, stream);
  buildA_gemm1_kernel<<<ABLOCKS + GBLOCKS, 256, 0, stream>>>(
      EI, bucketed, gcur, X, Wm[0], As[0], Ad[0], hA, esA, edA);
  bucketB_kernel<<<NBKT, 1024, 0, stream>>>(bucketed, gcur, rowptr, csr);
  agg_gemm_kernel<<<GBLOCKS, 256, 0, stream>>>(
      rowptr, csr, esA, edA, (const uint4*)hA, Bb[0],
      Wm[1], As[1], Ad[1], hB, esB, edB);
  agg_gemm_kernel<<<GBLOCKS, 256, 0, stream>>>(
      rowptr, csr, esB, edB, (const uint4*)hB, Bb[1],
      Wm[2], As[2], Ad[2], hA, esA, edA);
  agg3_pool_kernel<<<GBLOCKS, 256, 0, stream>>>(
      rowptr, csr, esA, edA, (const uint4*)hA, Bb[2], BT, pooled);
  final_kernel<<<(NB * NC + 255) / 256, 256, 0, stream>>>(pooled, BT, Wl, bl, (float*)d_out);
}